// Round 1
// baseline (89.969 us; speedup 1.0000x reference)
//
#include <hip/hip_runtime.h>

// Problem constants (match reference)
#define BATCH 32
#define CH 3
#define HH 512
#define WW 512
#define HWSZ (HH * WW)          // 262144 = 2^18
#define NCLS 8
#define PIX_PER_THREAD 4

__global__ __launch_bounds__(256) void affine_mask_kernel(
    const float* __restrict__ img,    // [B,3,H,W]
    const float* __restrict__ simg,   // [B,3,H,W]
    const float* __restrict__ Wp,     // [8,3,3]
    const float* __restrict__ bp,     // [8,3]
    const float* __restrict__ sigp,   // [1]
    float* __restrict__ out)          // [B,8,H,W]
{
    __shared__ float sW[NCLS][3][3];  // 72
    __shared__ float sB[NCLS][3];     // 24
    __shared__ float sScale;

    const int tid = threadIdx.x;
    if (tid < 72) {
        ((float*)sW)[tid] = Wp[tid];
    } else if (tid < 96) {
        ((float*)sB)[tid - 72] = bp[tid - 72];
    } else if (tid == 96) {
        float s = sigp[0];
        sScale = -1.0f / (2.0f * s * s);
    }
    __syncthreads();

    // group of 4 consecutive pixels
    const long g = (long)blockIdx.x * blockDim.x + tid;
    const long p = g * PIX_PER_THREAD;          // flat pixel index in [0, B*H*W)
    const int bidx = (int)(p >> 18);            // p / (H*W)
    const int rem  = (int)(p & (HWSZ - 1));     // p % (H*W)

    const float* xbase = img  + (size_t)bidx * CH * HWSZ + rem;
    const float* ybase = simg + (size_t)bidx * CH * HWSZ + rem;

    float4 x0 = *(const float4*)(xbase);
    float4 x1 = *(const float4*)(xbase + HWSZ);
    float4 x2 = *(const float4*)(xbase + 2 * HWSZ);
    float4 y0 = *(const float4*)(ybase);
    float4 y1 = *(const float4*)(ybase + HWSZ);
    float4 y2 = *(const float4*)(ybase + 2 * HWSZ);

    float X[3][4], Y[3][4];
    X[0][0] = x0.x; X[0][1] = x0.y; X[0][2] = x0.z; X[0][3] = x0.w;
    X[1][0] = x1.x; X[1][1] = x1.y; X[1][2] = x1.z; X[1][3] = x1.w;
    X[2][0] = x2.x; X[2][1] = x2.y; X[2][2] = x2.z; X[2][3] = x2.w;
    Y[0][0] = y0.x; Y[0][1] = y0.y; Y[0][2] = y0.z; Y[0][3] = y0.w;
    Y[1][0] = y1.x; Y[1][1] = y1.y; Y[1][2] = y1.z; Y[1][3] = y1.w;
    Y[2][0] = y2.x; Y[2][1] = y2.y; Y[2][2] = y2.z; Y[2][3] = y2.w;

    const float scale = sScale;
    float* obase = out + (size_t)bidx * NCLS * HWSZ + rem;

#pragma unroll
    for (int k = 0; k < NCLS; ++k) {
        float w[3][3], bb[3];
#pragma unroll
        for (int o = 0; o < 3; ++o) {
            bb[o] = sB[k][o];
#pragma unroll
            for (int c = 0; c < 3; ++c) w[o][c] = sW[k][o][c];
        }
        float rr[4];
#pragma unroll
        for (int j = 0; j < 4; ++j) {
            float acc = 0.0f;
#pragma unroll
            for (int o = 0; o < 3; ++o) {
                float d = fmaf(w[o][0], X[0][j],
                          fmaf(w[o][1], X[1][j],
                          fmaf(w[o][2], X[2][j], bb[o]))) - Y[o][j];
                acc = fmaf(d, d, acc);
            }
            rr[j] = acc * scale;
        }
        float4 r;
        r.x = rr[0]; r.y = rr[1]; r.z = rr[2]; r.w = rr[3];
        *(float4*)(obase + (size_t)k * HWSZ) = r;
    }
}

extern "C" void kernel_launch(void* const* d_in, const int* in_sizes, int n_in,
                              void* d_out, int out_size, void* d_ws, size_t ws_size,
                              hipStream_t stream) {
    const float* img  = (const float*)d_in[0];
    const float* simg = (const float*)d_in[1];
    const float* Wp   = (const float*)d_in[2];
    const float* bp   = (const float*)d_in[3];
    const float* sigp = (const float*)d_in[4];
    float* out = (float*)d_out;

    const long total_pix = (long)BATCH * HWSZ;                 // 8388608
    const long groups = total_pix / PIX_PER_THREAD;            // 2097152
    const int block = 256;
    const int grid = (int)(groups / block);                    // 8192, exact

    affine_mask_kernel<<<grid, block, 0, stream>>>(img, simg, Wp, bp, sigp, out);
}